// Round 6
// baseline (89.267 us; speedup 1.0000x reference)
//
#include <hip/hip_runtime.h>
#include <math.h>

#define NN    1000
#define NPAD  1024                   /* padded with 24 dummy gaussians       */
#define SPLIT 16                     /* waves per block = gaussian chunks    */
#define GPW   64                     /* gaussians per wave chunk (NPAD/16)   */
#define ITERS 4                      /* DIAGNOSTIC x4 repeat - see theory    */
#define LOG2E  1.4426950408889634f
#define LN2PI  1.8378770664093453f   /* log(2*pi) */

typedef float v2f __attribute__((ext_vector_type(2)));

__device__ __forceinline__ v2f pkfma(v2f a, v2f b, v2f c) { return __builtin_elementwise_fma(a, b, c); }
__device__ __forceinline__ v2f pkmax(v2f a, v2f b)        { return __builtin_elementwise_max(a, b); }
__device__ __forceinline__ v2f splat2(float s)            { return (v2f){s, s}; }
__device__ __forceinline__ void opaque(v2f& a)            { asm volatile("" : "+v"(a)); }

// ---- kernel 1: per-gaussian derived params (Cholesky form), 10 dwords/g ----
// k = K - u^2 - v^2,  u = p*x + q*y + u0,  v = r*y + v0
// gpA[n] = (p, q, u0, r)   gpB[n] = (v0, K, alpha, colR)   gpC[n] = (colG, colB)
__global__ __launch_bounds__(256) void splat_prep(
    const float* __restrict__ rho, const float* __restrict__ sigma,
    const float* __restrict__ coords, const float* __restrict__ alpha,
    const float* __restrict__ colors,
    float4* __restrict__ gpA, float4* __restrict__ gpB, float2* __restrict__ gpC)
{
    int n = blockIdx.x * 256 + threadIdx.x;
    if (n >= NPAD) return;
    if (n >= NN) {   // dummy: alpha = colors = 0, K very negative -> no-op
        gpA[n] = make_float4(0.f, 0.f, 0.f, 0.f);
        gpB[n] = make_float4(0.f, -1e30f, 0.f, 0.f);
        gpC[n] = make_float2(0.f, 0.f);
        return;
    }
    float sx = tanhf(sigma[2*n]   * 0.5f) + 1e-4f;
    float sy = tanhf(sigma[2*n+1] * 0.5f) + 1e-4f;
    float rho_a = 1.0f / (1.0f + expf(-rho[n])) + 1e-6f;   // sigmoid + EPS
    float cxx = sx*sx + 1e-6f;
    float cyy = sy*sy + 1e-6f;
    float cxy = sx*sy*rho_a;
    float det = cxx*cyy - cxy*cxy;
    float invdet = 1.0f / det;
    float hl = 0.5f * LOG2E;
    float a  = hl * cyy * invdet;
    float g  = -hl * cxy * invdet;
    float p  = sqrtf(a);
    float q  = g / p;
    float r  = sqrtf(hl / cyy);      // exact: b - q^2 = hl/cyy
    float cx = tanhf(coords[2*n])   - 0.5f;
    float cy = tanhf(coords[2*n+1]) - 0.5f;
    float u0 = p*cx + q*cy;
    float v0 = r*cy;
    float K  = (0.5f * logf(det + 1e-6f) - LN2PI) * LOG2E;
    float al = 1.0f / (1.0f + expf(-alpha[n]));
    float cr = 1.0f / (1.0f + expf(-colors[3*n]));
    float cg = 1.0f / (1.0f + expf(-colors[3*n+1]));
    float cb = 1.0f / (1.0f + expf(-colors[3*n+2]));
    gpA[n] = make_float4(p, q, u0, r);
    gpB[n] = make_float4(v0, K, al, cr);
    gpC[n] = make_float2(cg, cb);
}

// quadratic form for one gaussian, packed over 2 pixels
__device__ __forceinline__ v2f qform(float4 a, float4 b, v2f X, v2f Y) {
    v2f U = pkfma(splat2(a.x), X, pkfma(splat2(a.y), Y, splat2(a.z)));
    v2f V = pkfma(splat2(a.w), Y, splat2(b.x));
    return pkfma(U, -U, pkfma(V, -V, splat2(b.y)));
}

// ---- kernel 2: 128 px/block (2/thread packed), 16 waves x 64-g chunks ----
__global__ __launch_bounds__(1024, 8) void splat_main(
    const float4* __restrict__ gpA, const float4* __restrict__ gpB,
    const float2* __restrict__ gpC, const float2* __restrict__ xy2,
    float* __restrict__ out)
{
    const int tid  = threadIdx.x;
    const int wave = __builtin_amdgcn_readfirstlane(tid >> 6);
    const int lane = tid & 63;
    const int pbase = blockIdx.x * 128;
    const int p0 = pbase + lane;
    const int p1 = p0 + 64;

    float2 c0 = xy2[p0];
    float2 c1 = xy2[p1];
    const v2f X = (v2f){c0.x, c1.x};
    const v2f Y = (v2f){c0.y, c1.y};

    const float4* A = gpA + wave * GPW;   // wave-uniform bases -> s_load
    const float4* B = gpB + wave * GPW;
    const float2* C = gpC + wave * GPW;

    v2f m2, sa, sr, sg, sb;

    // DIAGNOSTIC: repeat identical work ITERS times so the dispatch ranks
    // above the harness's ~39us fill dispatches in rocprof top-5.
    // opaque() barriers block CSE across iterations; values are unchanged.
    for (int it = 0; it < ITERS; ++it) {
        m2 = splat2(-INFINITY);
        sa = splat2(0.f); sr = splat2(0.f); sg = splat2(0.f); sb = splat2(0.f);
        opaque(m2); opaque(sa); opaque(sr); opaque(sg); opaque(sb);

        for (int g = 0; g < GPW; g += 4) {
            const float4 a0 = A[g+0], a1 = A[g+1], a2 = A[g+2], a3 = A[g+3];
            const float4 b0 = B[g+0], b1 = B[g+1], b2 = B[g+2], b3 = B[g+3];
            const float2 e0 = C[g+0], e1 = C[g+1], e2 = C[g+2], e3 = C[g+3];

            v2f k0 = qform(a0, b0, X, Y);
            v2f k1 = qform(a1, b1, X, Y);
            v2f k2 = qform(a2, b2, X, Y);
            v2f k3 = qform(a3, b3, X, Y);
            v2f kb = pkmax(pkmax(k0, k1), pkmax(k2, k3));

            v2f mn  = pkmax(m2, kb);            // unconditional online rescale
            v2f dm  = m2 - mn;
            v2f s01 = (v2f){__builtin_amdgcn_exp2f(dm.x), __builtin_amdgcn_exp2f(dm.y)};
            sa *= s01; sr *= s01; sg *= s01; sb *= s01;
            m2 = mn;

            v2f t, e;
            t = k0 - m2; e = (v2f){__builtin_amdgcn_exp2f(t.x), __builtin_amdgcn_exp2f(t.y)};
            sa = pkfma(e, splat2(b0.z), sa); sr = pkfma(e, splat2(b0.w), sr);
            sg = pkfma(e, splat2(e0.x), sg); sb = pkfma(e, splat2(e0.y), sb);
            t = k1 - m2; e = (v2f){__builtin_amdgcn_exp2f(t.x), __builtin_amdgcn_exp2f(t.y)};
            sa = pkfma(e, splat2(b1.z), sa); sr = pkfma(e, splat2(b1.w), sr);
            sg = pkfma(e, splat2(e1.x), sg); sb = pkfma(e, splat2(e1.y), sb);
            t = k2 - m2; e = (v2f){__builtin_amdgcn_exp2f(t.x), __builtin_amdgcn_exp2f(t.y)};
            sa = pkfma(e, splat2(b2.z), sa); sr = pkfma(e, splat2(b2.w), sr);
            sg = pkfma(e, splat2(e2.x), sg); sb = pkfma(e, splat2(e2.y), sb);
            t = k3 - m2; e = (v2f){__builtin_amdgcn_exp2f(t.x), __builtin_amdgcn_exp2f(t.y)};
            sa = pkfma(e, splat2(b3.z), sa); sr = pkfma(e, splat2(b3.w), sr);
            sg = pkfma(e, splat2(e3.x), sg); sb = pkfma(e, splat2(e3.y), sb);
        }
        // keep each iteration's results live (prevents DCE of iters 0..2)
        asm volatile("" :: "v"(m2), "v"(sa), "v"(sr), "v"(sg), "v"(sb));
    }

    // ---- combine the 16 per-wave partial softmax states in LDS ----
    __shared__ float part[5][SPLIT][64][2];
    part[0][wave][lane][0] = m2.x;  part[0][wave][lane][1] = m2.y;
    part[1][wave][lane][0] = sa.x;  part[1][wave][lane][1] = sa.y;
    part[2][wave][lane][0] = sr.x;  part[2][wave][lane][1] = sr.y;
    part[3][wave][lane][0] = sg.x;  part[3][wave][lane][1] = sg.y;
    part[4][wave][lane][0] = sb.x;  part[4][wave][lane][1] = sb.y;
    __syncthreads();

    if (tid < 128) {
        const int half = tid >> 6, l = tid & 63;
        float M = part[0][0][l][half];
        #pragma unroll
        for (int w = 1; w < SPLIT; ++w) M = fmaxf(M, part[0][w][l][half]);
        float Aa = 0.f, R = 0.f, G = 0.f, Bb = 0.f;
        #pragma unroll
        for (int w = 0; w < SPLIT; ++w) {
            float s = __builtin_amdgcn_exp2f(part[0][w][l][half] - M);
            Aa = fmaf(part[1][w][l][half], s, Aa);
            R  = fmaf(part[2][w][l][half], s, R);
            G  = fmaf(part[3][w][l][half], s, G);
            Bb = fmaf(part[4][w][l][half], s, Bb);
        }
        float inv = 1.0f / (Aa + 1e-6f);
        int qx = pbase + half*64 + l;
        out[3*qx]   = R * inv;
        out[3*qx+1] = G * inv;
        out[3*qx+2] = Bb * inv;
    }
}

extern "C" void kernel_launch(void* const* d_in, const int* in_sizes, int n_in,
                              void* d_out, int out_size, void* d_ws, size_t ws_size,
                              hipStream_t stream) {
    const float* rho    = (const float*)d_in[0];
    const float* sigma  = (const float*)d_in[1];
    const float* coords = (const float*)d_in[2];
    const float* alpha  = (const float*)d_in[3];
    const float* colors = (const float*)d_in[4];
    const float* xy     = (const float*)d_in[5];
    float* out = (float*)d_out;

    char* ws = (char*)d_ws;                       // 40 KB scratch
    float4* gpA = (float4*)(ws);
    float4* gpB = (float4*)(ws + NPAD * 16);
    float2* gpC = (float2*)(ws + NPAD * 32);

    splat_prep<<<NPAD / 256, 256, 0, stream>>>(rho, sigma, coords, alpha, colors,
                                               gpA, gpB, gpC);
    // 65536 px / 128 px-per-block = 512 blocks; 16 waves/block, one 64-chunk each
    splat_main<<<65536 / 128, 1024, 0, stream>>>(gpA, gpB, gpC, (const float2*)xy, out);
}

// Round 7
// 33.126 us; speedup vs baseline: 2.6948x; 2.6948x over previous
//
#include <hip/hip_runtime.h>
#include <math.h>

#define NN     1000
#define NPAD   1024                  /* padded with 24 dummy gaussians       */
#define SPLIT  16                    /* waves per block = gaussian chunks    */
#define GPW    64                    /* gaussians per wave chunk (NPAD/16)   */
#define NBATCH (GPW/4)               /* 16 batches of 4 per wave             */
#define LOG2E  1.4426950408889634f
#define LN2PI  1.8378770664093453f   /* log(2*pi) */

typedef float v2f __attribute__((ext_vector_type(2)));

static __device__ __forceinline__ v2f pkfma(v2f a, v2f b, v2f c) { return __builtin_elementwise_fma(a, b, c); }
static __device__ __forceinline__ v2f pkmax(v2f a, v2f b)        { return __builtin_elementwise_max(a, b); }
static __device__ __forceinline__ v2f splat2(float s)            { return (v2f){s, s}; }

// ---- workspace layout: per batch of 4 gaussians, 80 dwords ----
// [ 0..47]: 4 x 6 DUPLICATED k-param pairs   (Q,Q, P,P, R,R, U0,U0, V0,V0, K,K)
// [48..79]: 4 x 4 DUPLICATED color pairs     (AL,AL, CR,CR, CG,CG, CB,CB)
// Duplication makes each param a legal 64-bit SGPR-pair operand for VOP3P
// (v_pk_*_f32), eliminating all splat v_movs; each op reads <=1 SGPR pair.
__global__ __launch_bounds__(256) void splat_prep(
    const float* __restrict__ rho, const float* __restrict__ sigma,
    const float* __restrict__ coords, const float* __restrict__ alpha,
    const float* __restrict__ colors, float* __restrict__ gd)
{
    int n = blockIdx.x * 256 + threadIdx.x;
    if (n >= NPAD) return;

    float p, q, r, u0, v0, K, al, cr, cg, cb;
    if (n >= NN) {   // dummy: never raises max (K=-1e30), contributes 0
        p = q = r = u0 = v0 = 0.f; K = -1e30f; al = cr = cg = cb = 0.f;
    } else {
        float sx = tanhf(sigma[2*n]   * 0.5f) + 1e-4f;
        float sy = tanhf(sigma[2*n+1] * 0.5f) + 1e-4f;
        float rho_a = 1.0f / (1.0f + expf(-rho[n])) + 1e-6f;   // sigmoid + EPS
        float cxx = sx*sx + 1e-6f;
        float cyy = sy*sy + 1e-6f;
        float cxy = sx*sy*rho_a;
        float det = cxx*cyy - cxy*cxy;
        float invdet = 1.0f / det;
        float hl = 0.5f * LOG2E;
        float a  = hl * cyy * invdet;
        float g  = -hl * cxy * invdet;
        p  = sqrtf(a);
        q  = g / p;
        r  = sqrtf(hl / cyy);        // exact: b - q^2 = hl/cyy
        float cx = tanhf(coords[2*n])   - 0.5f;
        float cy = tanhf(coords[2*n+1]) - 0.5f;
        u0 = p*cx + q*cy;
        v0 = r*cy;
        K  = (0.5f * logf(det + 1e-6f) - LN2PI) * LOG2E;
        al = 1.0f / (1.0f + expf(-alpha[n]));
        cr = 1.0f / (1.0f + expf(-colors[3*n]));
        cg = 1.0f / (1.0f + expf(-colors[3*n+1]));
        cb = 1.0f / (1.0f + expf(-colors[3*n+2]));
    }

    float* base = gd + (n >> 2) * 80;
    int j = n & 3;
    float* kp = base + j * 12;
    kp[0]=q;  kp[1]=q;  kp[2]=p;  kp[3]=p;  kp[4]=r;  kp[5]=r;
    kp[6]=u0; kp[7]=u0; kp[8]=v0; kp[9]=v0; kp[10]=K; kp[11]=K;
    float* cp = base + 48 + j * 8;
    cp[0]=al; cp[1]=al; cp[2]=cr; cp[3]=cr; cp[4]=cg; cp[5]=cg; cp[6]=cb; cp[7]=cb;
}

// k = K - u^2 - v^2, u = p*x + (q*y + u0), v = r*y + v0.
// Each op reads exactly one SGPR pair: Q,U0,P / R,V0 / K.
static __device__ __forceinline__ v2f gauss_k(const v2f* __restrict__ kp, v2f X, v2f Y) {
    v2f t = kp[0] * Y;          // v_pk_mul  (Q)
    t = t + kp[3];              // v_pk_add  (U0)
    v2f u = pkfma(kp[1], X, t); // v_pk_fma  (P)
    v2f w = kp[2] * Y;          // v_pk_mul  (R)
    v2f v = w + kp[4];          // v_pk_add  (V0)
    v2f k = pkfma(u, -u, kp[5]);// v_pk_fma  (K)
    return pkfma(v, -v, k);     // v_pk_fma  (no sgpr)
}

// ---- kernel 2: 128 px/block (2/thread packed), 16 waves x 64-g chunks ----
__global__ __launch_bounds__(1024, 8) void splat_main(
    const float* __restrict__ gd, const float2* __restrict__ xy2,
    float* __restrict__ out)
{
    const int tid  = threadIdx.x;
    const int wave = __builtin_amdgcn_readfirstlane(tid >> 6);
    const int lane = tid & 63;
    const int pbase = blockIdx.x * 128;
    const int p0 = pbase + lane;
    const int p1 = p0 + 64;

    float2 c0 = xy2[p0];
    float2 c1 = xy2[p1];
    const v2f X = (v2f){c0.x, c1.x};
    const v2f Y = (v2f){c0.y, c1.y};

    v2f m2 = splat2(-INFINITY);
    v2f sa = splat2(0.f), sr = splat2(0.f), sg = splat2(0.f), sb = splat2(0.f);

    const float* wbase = gd + wave * (NBATCH * 80);   // wave-uniform -> s_load

    for (int b = 0; b < NBATCH; ++b) {
        const float* bb = wbase + b * 80;
        const v2f* kp = (const v2f*)bb;
        const v2f* cp = (const v2f*)(bb + 48);

        v2f k0 = gauss_k(kp + 0,  X, Y);
        v2f k1 = gauss_k(kp + 6,  X, Y);
        v2f k2 = gauss_k(kp + 12, X, Y);
        v2f k3 = gauss_k(kp + 18, X, Y);
        v2f kb = pkmax(pkmax(k0, k1), pkmax(k2, k3));

        v2f mn  = pkmax(m2, kb);            // unconditional online rescale
        v2f dm  = m2 - mn;
        v2f s01 = (v2f){__builtin_amdgcn_exp2f(dm.x), __builtin_amdgcn_exp2f(dm.y)};
        sa *= s01; sr *= s01; sg *= s01; sb *= s01;
        m2 = mn;

        v2f t, e;
        t = k0 - m2; e = (v2f){__builtin_amdgcn_exp2f(t.x), __builtin_amdgcn_exp2f(t.y)};
        sa = pkfma(e, cp[0],  sa); sr = pkfma(e, cp[1],  sr);
        sg = pkfma(e, cp[2],  sg); sb = pkfma(e, cp[3],  sb);
        t = k1 - m2; e = (v2f){__builtin_amdgcn_exp2f(t.x), __builtin_amdgcn_exp2f(t.y)};
        sa = pkfma(e, cp[4],  sa); sr = pkfma(e, cp[5],  sr);
        sg = pkfma(e, cp[6],  sg); sb = pkfma(e, cp[7],  sb);
        t = k2 - m2; e = (v2f){__builtin_amdgcn_exp2f(t.x), __builtin_amdgcn_exp2f(t.y)};
        sa = pkfma(e, cp[8],  sa); sr = pkfma(e, cp[9],  sr);
        sg = pkfma(e, cp[10], sg); sb = pkfma(e, cp[11], sb);
        t = k3 - m2; e = (v2f){__builtin_amdgcn_exp2f(t.x), __builtin_amdgcn_exp2f(t.y)};
        sa = pkfma(e, cp[12], sa); sr = pkfma(e, cp[13], sr);
        sg = pkfma(e, cp[14], sg); sb = pkfma(e, cp[15], sb);
    }

    // ---- combine the 16 per-wave partial softmax states in LDS ----
    __shared__ float part[5][SPLIT][64][2];
    part[0][wave][lane][0] = m2.x;  part[0][wave][lane][1] = m2.y;
    part[1][wave][lane][0] = sa.x;  part[1][wave][lane][1] = sa.y;
    part[2][wave][lane][0] = sr.x;  part[2][wave][lane][1] = sr.y;
    part[3][wave][lane][0] = sg.x;  part[3][wave][lane][1] = sg.y;
    part[4][wave][lane][0] = sb.x;  part[4][wave][lane][1] = sb.y;
    __syncthreads();

    if (tid < 128) {
        const int half = tid >> 6, l = tid & 63;
        float M = part[0][0][l][half];
        #pragma unroll
        for (int w = 1; w < SPLIT; ++w) M = fmaxf(M, part[0][w][l][half]);
        float Aa = 0.f, R = 0.f, G = 0.f, Bb = 0.f;
        #pragma unroll
        for (int w = 0; w < SPLIT; ++w) {
            float s = __builtin_amdgcn_exp2f(part[0][w][l][half] - M);
            Aa = fmaf(part[1][w][l][half], s, Aa);
            R  = fmaf(part[2][w][l][half], s, R);
            G  = fmaf(part[3][w][l][half], s, G);
            Bb = fmaf(part[4][w][l][half], s, Bb);
        }
        float inv = 1.0f / (Aa + 1e-6f);
        int qx = pbase + half*64 + l;
        out[3*qx]   = R * inv;
        out[3*qx+1] = G * inv;
        out[3*qx+2] = Bb * inv;
    }
}

extern "C" void kernel_launch(void* const* d_in, const int* in_sizes, int n_in,
                              void* d_out, int out_size, void* d_ws, size_t ws_size,
                              hipStream_t stream) {
    const float* rho    = (const float*)d_in[0];
    const float* sigma  = (const float*)d_in[1];
    const float* coords = (const float*)d_in[2];
    const float* alpha  = (const float*)d_in[3];
    const float* colors = (const float*)d_in[4];
    const float* xy     = (const float*)d_in[5];
    float* out = (float*)d_out;
    float* gd  = (float*)d_ws;    // NPAD/4 batches * 80 dwords = 80 KB scratch

    splat_prep<<<NPAD / 256, 256, 0, stream>>>(rho, sigma, coords, alpha, colors, gd);
    // 65536 px / 128 px-per-block = 512 blocks; 16 waves/block, one 64-chunk each
    splat_main<<<65536 / 128, 1024, 0, stream>>>(gd, (const float2*)xy, out);
}